// Round 1
// baseline (94.134 us; speedup 1.0000x reference)
//
#include <hip/hip_runtime.h>
#include <math.h>

#define MARGIN 0.3f
#define NT   1024   // threads (16 waves, 1 workgroup, 1 CU)
#define EPT  16     // elements/thread (n <= 16384)
#define NB   1024   // value bins (== NT so scans are 1 bin/thread)
#define KMAX 8192   // min(P,Q) <= n/2

// Single-dispatch fused kernel:
//   total = sum_{i in pos, j in neg} max(0, (MARGIN + s_j) - s_i)
// computed exactly via bucket + per-bin double prefix sums over the
// SMALLER class (K <= 8192), streamed against the larger class.
// No workspace, no memset, no global atomics, out[0] written directly.
__global__ __launch_bounds__(NT) void fused_loss_kernel(
        const float* __restrict__ inputs,
        const int*   __restrict__ targets,
        float*       __restrict__ out,
        int n)
{
    __shared__ float        sorted[KMAX];     // 32 KB bin-grouped values
    __shared__ unsigned int binoff[NB];       //  4 KB hist -> scatter cursor
    __shared__ unsigned int start[NB + 1];    //  4 KB exclusive bin starts
    __shared__ double       psum[NB + 1];     //  8 KB exclusive bin prefix sums
    __shared__ double       dscr[16];
    __shared__ unsigned int uscr[16];
    __shared__ unsigned int sPQ[2];

    const int tid  = threadIdx.x;
    const int lane = tid & 63;
    const int wv   = tid >> 6;

    binoff[tid] = 0u;   // NB == NT

    // ---- phase 1: load + sigmoid + classify, all kept in registers ----
    float sv[EPT];
    unsigned int posbits = 0u, negbits = 0u;
    #pragma unroll
    for (int k = 0; k < EPT; ++k) {
        int idx = tid + k * NT;
        float x = 0.0f; int t = -1;
        if (idx < n) { x = inputs[idx]; t = targets[idx]; }
        sv[k] = 1.0f / (1.0f + expf(-x));
        if (t == 1) posbits |= (1u << k);
        else if (t == 0) negbits |= (1u << k);
    }

    // ---- count P, Q (packed 16+16 bit, block reduce) ----
    unsigned int cnt2 = ((unsigned int)__popc(posbits) << 16) | (unsigned int)__popc(negbits);
    for (int off = 32; off > 0; off >>= 1)
        cnt2 += __shfl_down(cnt2, off, 64);
    if (lane == 0) uscr[wv] = cnt2;
    __syncthreads();
    if (tid == 0) {
        unsigned int tot = 0u;
        for (int w = 0; w < 16; ++w) tot += uscr[w];
        sPQ[0] = tot >> 16; sPQ[1] = tot & 0xffffu;
    }
    __syncthreads();
    const unsigned int P = sPQ[0], Q = sPQ[1];
    if (P == 0u || Q == 0u) { if (tid == 0) out[0] = 0.0f; return; }

    // sort side = smaller class. pos value a = s, neg value b = MARGIN + s.
    const bool sortPos = (P <= Q);
    const unsigned int K        = sortPos ? P : Q;
    const unsigned int sortbits = sortPos ? posbits : negbits;
    const unsigned int strmbits = sortPos ? negbits : posbits;
    const float sortAdd = sortPos ? 0.0f : MARGIN;
    const float strmAdd = sortPos ? MARGIN : 0.0f;
    const float lo      = sortAdd;           // sorted values span (lo, lo+1)
    const float scale   = (float)NB;

    // ---- histogram of sort-side values ----
    #pragma unroll
    for (int k = 0; k < EPT; ++k) {
        if (sortbits & (1u << k)) {
            float v = sv[k] + sortAdd;
            int b = (int)((v - lo) * scale);
            b = min(max(b, 0), NB - 1);
            atomicAdd(&binoff[b], 1u);
        }
    }
    __syncthreads();

    // ---- exclusive scan of bin counts (1 bin/thread) ----
    unsigned int c  = binoff[tid];
    unsigned int iv = c;
    for (int off = 1; off < 64; off <<= 1) {
        unsigned int t = __shfl_up(iv, off, 64);
        if (lane >= off) iv += t;
    }
    if (lane == 63) uscr[wv] = iv;
    __syncthreads();
    if (tid == 0) {
        unsigned int accu = 0u;
        for (int w = 0; w < 16; ++w) { unsigned int t = uscr[w]; uscr[w] = accu; accu += t; }
    }
    __syncthreads();
    const unsigned int excl = uscr[wv] + iv - c;
    start[tid] = excl;
    if (tid == NT - 1) start[NB] = excl + c;   // == K
    __syncthreads();
    binoff[tid] = excl;                        // scatter cursors
    __syncthreads();

    // ---- scatter into bin-grouped array (order within bin arbitrary) ----
    #pragma unroll
    for (int k = 0; k < EPT; ++k) {
        if (sortbits & (1u << k)) {
            float v = sv[k] + sortAdd;
            int b = (int)((v - lo) * scale);
            b = min(max(b, 0), NB - 1);
            unsigned int p = atomicAdd(&binoff[b], 1u);
            sorted[p] = v;
        }
    }
    __syncthreads();

    // ---- per-bin double sums -> exclusive prefix over bins ----
    double bsum = 0.0;
    {
        unsigned int s0 = start[tid], s1 = start[tid + 1];
        for (unsigned int j = s0; j < s1; ++j) bsum += (double)sorted[j];
    }
    double dv = bsum;
    for (int off = 1; off < 64; off <<= 1) {
        double t = __shfl_up(dv, off, 64);
        if (lane >= off) dv += t;
    }
    if (lane == 63) dscr[wv] = dv;
    __syncthreads();
    if (tid == 0) {
        double accd = 0.0;
        for (int w = 0; w < 16; ++w) { double t = dscr[w]; dscr[w] = accd; accd += t; }
    }
    __syncthreads();
    const double dexcl = dscr[wv] + dv - bsum;
    psum[tid] = dexcl;
    if (tid == NT - 1) psum[NB] = dexcl + bsum;
    __syncthreads();

    // ---- stream the larger class: bin lookup + exact boundary-bin scan ----
    // bin() is monotone in f32, so bin(v)<bin(u) => v<u and bin(v)>bin(u) => v>u;
    // ties (v==u) contribute 0 either way, so boundary handling is exact.
    const double Stot = psum[NB];
    double acc = 0.0;
    #pragma unroll
    for (int k = 0; k < EPT; ++k) {
        if (strmbits & (1u << k)) {
            float u = sv[k] + strmAdd;
            int b = (int)((u - lo) * scale);
            b = min(max(b, 0), NB - 1);
            unsigned int s0 = start[b], s1 = start[b + 1];
            if (sortPos) {
                // u is a neg value b_j; term = sum_{a < u} (u - a)
                unsigned int cb = s0; double S = psum[b];
                for (unsigned int j = s0; j < s1; ++j) {
                    float vv = sorted[j];
                    if (vv < u) { cb++; S += (double)vv; }
                }
                acc += (double)cb * (double)u - S;
            } else {
                // u is a pos value a_i; term = sum_{b > u} (b - u)
                unsigned int ch = K - s1; double S = Stot - psum[b + 1];
                for (unsigned int j = s0; j < s1; ++j) {
                    float vv = sorted[j];
                    if (vv > u) { ch++; S += (double)vv; }
                }
                acc += S - (double)ch * (double)u;
            }
        }
    }

    // ---- block reduction (double) + finalize ----
    for (int off = 32; off > 0; off >>= 1)
        acc += __shfl_down(acc, off, 64);
    __syncthreads();
    if (lane == 0) dscr[wv] = acc;
    __syncthreads();
    if (tid == 0) {
        double tot = 0.0;
        for (int w = 0; w < 16; ++w) tot += dscr[w];
        out[0] = (float)(tot / ((double)P * (double)Q));
    }
}

extern "C" void kernel_launch(void* const* d_in, const int* in_sizes, int n_in,
                              void* d_out, int out_size, void* d_ws, size_t ws_size,
                              hipStream_t stream) {
    (void)n_in; (void)out_size; (void)d_ws; (void)ws_size;
    const float* inputs  = (const float*)d_in[0];
    const int*   targets = (const int*)d_in[1];
    int n = in_sizes[0];
    fused_loss_kernel<<<1, NT, 0, stream>>>(inputs, targets, (float*)d_out, n);
}